// Round 4
// baseline (296.727 us; speedup 1.0000x reference)
//
#include <hip/hip_runtime.h>
#include <math.h>

#define QR_M 512
#define QR_N 26
#define OUTC 512

using half8_t = __attribute__((ext_vector_type(8))) _Float16;
using f32x4   = __attribute__((ext_vector_type(4))) float;

// ---------------------------------------------------------------------------
// Kernel 1: Householder QR of (w + 1e-8), 512x26, ONE wave (64 threads),
// 8 rows per thread (row = i*64 + t). All reductions are in-register 64-lane
// shfl_xor butterflies -> zero barriers in the factorization loop, and only
// ONE wave's worth of DS-pipe traffic (the 512-thread variant paid 8x DS
// occupancy ~ 40+ us; this is ~5 us). a[8][26] = 208 VGPR fits the 512-VGPR
// single-wave budget (passed in round 2, no spill).
// LAPACK slarfg sign convention: beta = -sign(alpha)*||x||. Q = A * R^{-1}
// via per-row forward substitution (cond(A)~1.6 -> ~1e-6 error).
// Emits Q as f16 row-major [512][32], k=26..31 zero-padded (MFMA B^T layout).
// ---------------------------------------------------------------------------
__global__ __launch_bounds__(64) void qr_kernel(const float* __restrict__ w,
                                                _Float16* __restrict__ qf) {
  const int t = threadIdx.x;  // 0..63; thread owns rows i*64+t, i=0..7

  float a[8][QR_N];
#pragma unroll
  for (int i = 0; i < 8; ++i) {
    const float2* wp = reinterpret_cast<const float2*>(w + (size_t)(i * 64 + t) * QR_N);
#pragma unroll
    for (int c2 = 0; c2 < QR_N / 2; ++c2) {
      float2 v = wp[c2];
      a[i][2 * c2]     = v.x + 1e-8f;
      a[i][2 * c2 + 1] = v.y + 1e-8f;
    }
  }

  __shared__ float Rl[QR_N][QR_N + 1];

#pragma unroll
  for (int j = 0; j < QR_N; ++j) {
    // alpha = current diagonal entry (row j lives at i=0, lane j)
    const float alpha = __shfl(a[0][j], j);
    // ||A[j:,j]||^2 : i=0 rows are t (mask t>=j); i>=1 rows are >=64 (always in)
    float sq = (t >= j) ? a[0][j] * a[0][j] : 0.0f;
#pragma unroll
    for (int i = 1; i < 8; ++i) sq += a[i][j] * a[i][j];
#pragma unroll
    for (int s = 32; s >= 1; s >>= 1) sq += __shfl_xor(sq, s);

    const float norm  = sqrtf(sq);
    const float beta  = (alpha >= 0.0f) ? -norm : norm;  // -sign(alpha)*norm
    const float tau   = (beta - alpha) / beta;
    const float scale = 1.0f / (alpha - beta);

    // Householder vector elements for this thread's rows; v[j]=1 implicit
    float ve[8];
    {
      const float av = a[0][j] * scale;
      ve[0] = (t > j) ? av : ((t == j) ? 1.0f : 0.0f);
      if (t > j)  a[0][j] = av;
      if (t == j) a[0][j] = beta;  // R diagonal
    }
#pragma unroll
    for (int i = 1; i < 8; ++i) { a[i][j] *= scale; ve[i] = a[i][j]; }

    // trailing update: A[:,c] -= tau * (v^T A[:,c]) * v
#pragma unroll
    for (int c = j + 1; c < QR_N; ++c) {
      float p = ve[0] * a[0][c];
#pragma unroll
      for (int i = 1; i < 8; ++i) p += ve[i] * a[i][c];
#pragma unroll
      for (int s = 32; s >= 1; s >>= 1) p += __shfl_xor(p, s);
      const float tw = tau * p;
#pragma unroll
      for (int i = 0; i < 8; ++i) a[i][c] -= tw * ve[i];
    }
  }

  // stage R (rows 0..25 = i=0 lanes 0..25) to LDS for the solve
  if (t < QR_N) {
#pragma unroll
    for (int c = 0; c < QR_N; ++c) Rl[t][c] = a[0][c];
  }
  __syncthreads();

  float rinv[QR_N];
#pragma unroll
  for (int c = 0; c < QR_N; ++c) rinv[c] = 1.0f / Rl[c][c];

  // Q row r: solve y * R = A_orig[r,:]; write as f16 with K padded to 32
#pragma unroll
  for (int i = 0; i < 8; ++i) {
    const int r = i * 64 + t;
    float y[QR_N];
    const float2* wp = reinterpret_cast<const float2*>(w + (size_t)r * QR_N);
#pragma unroll
    for (int c2 = 0; c2 < QR_N / 2; ++c2) {
      float2 v = wp[c2];
      y[2 * c2]     = v.x + 1e-8f;
      y[2 * c2 + 1] = v.y + 1e-8f;
    }
#pragma unroll
    for (int c = 0; c < QR_N; ++c) {
      float s = y[c];
#pragma unroll
      for (int k = 0; k < c; ++k) s -= y[k] * Rl[k][c];
      y[c] = s * rinv[c];
    }
    _Float16* qrow = qf + (size_t)r * 32;
#pragma unroll
    for (int c = 0; c < QR_N; ++c) qrow[c] = (_Float16)y[c];
#pragma unroll
    for (int c = QR_N; c < 32; ++c) qrow[c] = (_Float16)0.0f;
  }
}

// ---------------------------------------------------------------------------
// Kernel 2 (unchanged from round 3): out[b,o] = sum_d x[b,d] * Q[o,d] via
// mfma_f32_16x16x32_f16 with LDS-transposed epilogue for fully-coalesced
// dwordx4 stores. Block = 256 thr / 4 waves, 32 rows x 512 cols per iter.
// ---------------------------------------------------------------------------
__global__ __launch_bounds__(256, 4) void dir_matmul(const float* __restrict__ x,
                                                     const _Float16* __restrict__ qf,
                                                     float* __restrict__ out,
                                                     int nblk32) {
  const int tid   = threadIdx.x;
  const int wid   = tid >> 6;
  const int l     = tid & 63;
  const int rloc  = l & 15;
  const int grp   = l >> 4;
  const int k0    = grp * 8;
  const int rhalf = (wid >> 1) * 16;   // row half: 0 or 16
  const int chalf = (wid & 1) * 256;   // col half: 0 or 256
  const int t2b   = (wid & 1) * 16;    // N-tile base

  __shared__ float tile[4][16 * 132];  // per-wave 16x128 f32, pad 4
  float* tw = tile[wid];

  // preload this wave's 16 B-fragments (Q) — reused across iterations
  half8_t bq[16];
#pragma unroll
  for (int t2 = 0; t2 < 16; ++t2)
    bq[t2] = *reinterpret_cast<const half8_t*>(
        qf + (size_t)((t2b + t2) * 16 + rloc) * 32 + k0);

  for (int rb = blockIdx.x; rb < nblk32; rb += gridDim.x) {
    const int row = rb * 32 + rhalf + rloc;
    // A fragment: x[row][k0..k0+7] as f16; k>=26 zeroed
    half8_t av;
    const float* xp = x + (size_t)row * QR_N + k0;
    if (grp < 3) {
#pragma unroll
      for (int e = 0; e < 4; ++e) {
        float2 v = *reinterpret_cast<const float2*>(xp + 2 * e);
        av[2 * e]     = (_Float16)v.x;
        av[2 * e + 1] = (_Float16)v.y;
      }
    } else {
      float2 v = *reinterpret_cast<const float2*>(xp);
      av[0] = (_Float16)v.x; av[1] = (_Float16)v.y;
#pragma unroll
      for (int e = 2; e < 8; ++e) av[e] = (_Float16)0.0f;
    }

#pragma unroll
    for (int cc = 0; cc < 2; ++cc) {
      // 8 MFMA tiles -> LDS (transposed staging)
#pragma unroll
      for (int tt = 0; tt < 8; ++tt) {
        f32x4 acc = {0.0f, 0.0f, 0.0f, 0.0f};
        acc = __builtin_amdgcn_mfma_f32_16x16x32_f16(av, bq[cc * 8 + tt], acc, 0, 0, 0);
#pragma unroll
        for (int j = 0; j < 4; ++j)
          tw[(grp * 4 + j) * 132 + tt * 16 + rloc] = acc[j];
      }
      __syncthreads();
      // coalesced read-back + global float4 stores
#pragma unroll
      for (int it = 0; it < 8; ++it) {
        const int r  = it * 2 + (l >> 5);
        const int cg = l & 31;
        f32x4 v = *reinterpret_cast<const f32x4*>(&tw[r * 132 + 4 * cg]);
        *reinterpret_cast<f32x4*>(
            out + (size_t)(rb * 32 + rhalf + r) * OUTC + chalf + cc * 128 + 4 * cg) = v;
      }
      __syncthreads();
    }
  }
}

extern "C" void kernel_launch(void* const* d_in, const int* in_sizes, int n_in,
                              void* d_out, int out_size, void* d_ws, size_t ws_size,
                              hipStream_t stream) {
  const float* input  = (const float*)d_in[0];   // [B, 26] f32
  const float* weight = (const float*)d_in[1];   // [512, 26] f32
  float* out = (float*)d_out;                    // [B, 512] f32
  _Float16* qf = (_Float16*)d_ws;                // [512][32] f16 scratch (32 KB)

  const int B = in_sizes[0] / QR_N;              // 262144
  const int nblk32 = B / 32;                     // 8192

  qr_kernel<<<1, 64, 0, stream>>>(weight, qf);
  dir_matmul<<<2048, 256, 0, stream>>>(input, qf, out, nblk32);
}

// Round 7
// 202.677 us; speedup vs baseline: 1.4640x; 1.4640x over previous
//
#include <hip/hip_runtime.h>
#include <math.h>

// Round-7: byte-equivalent revert to the round-3 known-good pair (201.9 us,
// passed). Serves as pod-wedge control after two same-handle timeouts.

#define QR_M 512
#define QR_N 26
#define OUTC 512

using half8_t = __attribute__((ext_vector_type(8))) _Float16;
using f32x4   = __attribute__((ext_vector_type(4))) float;

// ---------------------------------------------------------------------------
// Kernel 1: Householder QR of (w + 1e-8), 512x26, 512 threads (one row per
// thread, 26 VGPR working set). LAPACK slarfg sign convention:
// beta = -sign(alpha)*||x||. Q = A * R^{-1} via per-row forward substitution
// (cond(A)~1.6 -> ~1e-6 error). Emits Q as f16 row-major [512][32],
// k=26..31 zero-padded (MFMA B^T fragment layout). Proven in rounds 1/3.
// ---------------------------------------------------------------------------
__global__ __launch_bounds__(512) void qr_kernel(const float* __restrict__ w,
                                                 _Float16* __restrict__ qf) {
  const int r = threadIdx.x;      // row 0..511
  const int lane = r & 63;
  const int wid = r >> 6;         // 8 waves

  __shared__ float part[QR_N][8]; // cross-wave reduction slots
  __shared__ float dotv[QR_N];
  __shared__ float s_alpha;
  __shared__ float Rl[QR_N][QR_N + 1];

  float a[QR_N];
#pragma unroll
  for (int c = 0; c < QR_N; ++c) a[c] = w[r * QR_N + c] + 1e-8f;

#pragma unroll
  for (int j = 0; j < QR_N; ++j) {
    if (r == j) s_alpha = a[j];
    float sq = (r >= j) ? a[j] * a[j] : 0.0f;
#pragma unroll
    for (int s = 32; s >= 1; s >>= 1) sq += __shfl_xor(sq, s);
    if (lane == 0) part[0][wid] = sq;
    __syncthreads();
    float nrm2 = 0.0f;
#pragma unroll
    for (int t = 0; t < 8; ++t) nrm2 += part[0][t];
    const float alpha = s_alpha;
    const float norm  = sqrtf(nrm2);
    const float beta  = (alpha >= 0.0f) ? -norm : norm; // -sign(alpha)*norm
    const float tau   = (beta - alpha) / beta;
    const float scale = 1.0f / (alpha - beta);
    float ve;
    if (r > j)       { a[j] *= scale; ve = a[j]; }
    else if (r == j) { ve = 1.0f; a[j] = beta; } // R diagonal
    else             { ve = 0.0f; }
#pragma unroll
    for (int c = j + 1; c < QR_N; ++c) {
      float p = ve * a[c];
#pragma unroll
      for (int s = 32; s >= 1; s >>= 1) p += __shfl_xor(p, s);
      if (lane == 0) part[c][wid] = p;
    }
    __syncthreads();
    if (r > j && r < QR_N) {
      float d = 0.0f;
#pragma unroll
      for (int t = 0; t < 8; ++t) d += part[r][t];
      dotv[r] = d * tau;
    }
    __syncthreads();
#pragma unroll
    for (int c = j + 1; c < QR_N; ++c) a[c] -= dotv[c] * ve;
  }

  if (r < QR_N) {
#pragma unroll
    for (int c = 0; c < QR_N; ++c) Rl[r][c] = a[c];
  }
  __syncthreads();

  // Q row r: solve y * R = A_orig[r,:] (forward substitution)
  float y[QR_N];
#pragma unroll
  for (int c = 0; c < QR_N; ++c) y[c] = w[r * QR_N + c] + 1e-8f;
#pragma unroll
  for (int c = 0; c < QR_N; ++c) {
    float s = y[c];
#pragma unroll
    for (int k = 0; k < c; ++k) s -= y[k] * Rl[k][c];
    y[c] = s / Rl[c][c];
  }
  _Float16* qrow = qf + (size_t)r * 32;
#pragma unroll
  for (int c = 0; c < QR_N; ++c) qrow[c] = (_Float16)y[c];
#pragma unroll
  for (int c = QR_N; c < 32; ++c) qrow[c] = (_Float16)0.0f;
}

// ---------------------------------------------------------------------------
// Kernel 2: out[b,o] = sum_d x[b,d] * Q[o,d] via mfma_f32_16x16x32_f16,
// LDS-transposed epilogue for fully-coalesced dwordx4 stores.
// Block = 256 thr / 4 waves, 32 rows x 512 cols per iteration. Proven r3/r4.
// ---------------------------------------------------------------------------
__global__ __launch_bounds__(256, 4) void dir_matmul(const float* __restrict__ x,
                                                     const _Float16* __restrict__ qf,
                                                     float* __restrict__ out,
                                                     int nblk32) {
  const int tid   = threadIdx.x;
  const int wid   = tid >> 6;
  const int l     = tid & 63;
  const int rloc  = l & 15;
  const int grp   = l >> 4;
  const int k0    = grp * 8;
  const int rhalf = (wid >> 1) * 16;   // row half: 0 or 16
  const int chalf = (wid & 1) * 256;   // col half: 0 or 256
  const int t2b   = (wid & 1) * 16;    // N-tile base

  __shared__ float tile[4][16 * 132];  // per-wave 16x128 f32, pad 4
  float* tw = tile[wid];

  half8_t bq[16];
#pragma unroll
  for (int t2 = 0; t2 < 16; ++t2)
    bq[t2] = *reinterpret_cast<const half8_t*>(
        qf + (size_t)((t2b + t2) * 16 + rloc) * 32 + k0);

  for (int rb = blockIdx.x; rb < nblk32; rb += gridDim.x) {
    const int row = rb * 32 + rhalf + rloc;
    half8_t av;
    const float* xp = x + (size_t)row * QR_N + k0;
    if (grp < 3) {
#pragma unroll
      for (int e = 0; e < 4; ++e) {
        float2 v = *reinterpret_cast<const float2*>(xp + 2 * e);
        av[2 * e]     = (_Float16)v.x;
        av[2 * e + 1] = (_Float16)v.y;
      }
    } else {
      float2 v = *reinterpret_cast<const float2*>(xp);
      av[0] = (_Float16)v.x; av[1] = (_Float16)v.y;
#pragma unroll
      for (int e = 2; e < 8; ++e) av[e] = (_Float16)0.0f;
    }

#pragma unroll
    for (int cc = 0; cc < 2; ++cc) {
#pragma unroll
      for (int tt = 0; tt < 8; ++tt) {
        f32x4 acc = {0.0f, 0.0f, 0.0f, 0.0f};
        acc = __builtin_amdgcn_mfma_f32_16x16x32_f16(av, bq[cc * 8 + tt], acc, 0, 0, 0);
#pragma unroll
        for (int j = 0; j < 4; ++j)
          tw[(grp * 4 + j) * 132 + tt * 16 + rloc] = acc[j];
      }
      __syncthreads();
#pragma unroll
      for (int it = 0; it < 8; ++it) {
        const int r  = it * 2 + (l >> 5);
        const int cg = l & 31;
        f32x4 v = *reinterpret_cast<const f32x4*>(&tw[r * 132 + 4 * cg]);
        *reinterpret_cast<f32x4*>(
            out + (size_t)(rb * 32 + rhalf + r) * OUTC + chalf + cc * 128 + 4 * cg) = v;
      }
      __syncthreads();
    }
  }
}

extern "C" void kernel_launch(void* const* d_in, const int* in_sizes, int n_in,
                              void* d_out, int out_size, void* d_ws, size_t ws_size,
                              hipStream_t stream) {
  const float* input  = (const float*)d_in[0];   // [B, 26] f32
  const float* weight = (const float*)d_in[1];   // [512, 26] f32
  float* out = (float*)d_out;                    // [B, 512] f32
  _Float16* qf = (_Float16*)d_ws;                // [512][32] f16 scratch (32 KB)

  const int B = in_sizes[0] / QR_N;              // 262144
  const int nblk32 = B / 32;                     // 8192

  qr_kernel<<<1, 512, 0, stream>>>(weight, qf);
  dir_matmul<<<2048, 256, 0, stream>>>(input, qf, out, nblk32);
}

// Round 8
// 157.267 us; speedup vs baseline: 1.8868x; 1.2887x over previous
//
#include <hip/hip_runtime.h>
#include <math.h>

#define QR_M 512
#define QR_N 26
#define OUTC 512

using half8_t = __attribute__((ext_vector_type(8))) _Float16;
using f32x4   = __attribute__((ext_vector_type(4))) float;

// ---------------------------------------------------------------------------
// Kernel 1: QR via Gram-domain Householder simulation. 512 threads.
//  Phase 1: stage A = w + 1e-8 into LDS As[512][27] (coalesced float2 loads).
//  Phase 2: G0 = A^T A (351 upper-tri entries, one thread each, 512 FMA from
//           LDS); T = top-26 rows of A.
//  Phase 3 (wave 0, lanes 0..25 = columns): exact 26-step Householder
//           recursion in 26-dim space:
//             trailG[j,c] = G0[j,c] - sum_{r<j} R[r,j] R[r,c]   (orthogonal
//               invariance of the Gram; rows < j are finalized R rows)
//             nsq = trailG[j,j]; alpha = T[j,j]
//             beta = -sign(alpha)*sqrt(nsq)  (LAPACK slarfg sign)
//             tau = (beta-alpha)/beta; scale = 1/(alpha-beta)
//             w_c = (trailG[j,c] - beta*T[j,c])*scale
//             R[j,c] = T[j,c] - tau*w_c ; R[j,j] = beta
//             T[r,c] -= tau*w_c*v_top[r], v_top[r]=T[r,j]*scale (r>j), 1 (r=j)
//           Exact same R (incl. diagonal signs) as Householder on 512 rows.
//  Phase 4: Q row r = forward-substitution solve y*R = A[r,:] (cond~1.6),
//           emit Q as f16 row-major [512][32], k=26..31 zero-padded.
// Replaces ~16.8k wave-serialized shfl butterflies with a 26-dim recursion.
// ---------------------------------------------------------------------------
__global__ __launch_bounds__(512) void qr_kernel(const float* __restrict__ w,
                                                 _Float16* __restrict__ qf) {
  const int tid  = threadIdx.x;
  const int lane = tid & 63;
  const int wid  = tid >> 6;

  __shared__ float As[QR_M][QR_N + 1];   // 55.3 KB
  __shared__ float G[QR_N][QR_N + 1];
  __shared__ float Ts[QR_N][QR_N + 1];
  __shared__ float Rl[QR_N][QR_N + 1];

  // Phase 1: stage A (+1e-8) into LDS
  {
    const float2* wp = reinterpret_cast<const float2*>(w + (size_t)tid * QR_N);
#pragma unroll
    for (int c2 = 0; c2 < QR_N / 2; ++c2) {
      float2 v = wp[c2];
      As[tid][2 * c2]     = v.x + 1e-8f;
      As[tid][2 * c2 + 1] = v.y + 1e-8f;
    }
  }
  __syncthreads();

  // Phase 2: Gram matrix (upper triangle) + T init
  for (int t = tid; t < QR_N * QR_N; t += 512) {
    const int c = t / QR_N;
    const int d = t - c * QR_N;
    if (d >= c) {
      float acc = 0.0f;
      for (int r = 0; r < QR_M; ++r) acc += As[r][c] * As[r][d];
      G[c][d] = acc;
      G[d][c] = acc;
    }
  }
  if (tid < QR_N) {
#pragma unroll
    for (int c = 0; c < QR_N; ++c) Ts[tid][c] = As[tid][c];
  }
  __syncthreads();

  // Phase 3: 26-step recursion on wave 0, lane c = column c
  if (wid == 0 && lane < QR_N) {
    const int c = lane;
    for (int j = 0; j < QR_N; ++j) {
      // trailing Gram entry for (j, c)
      float tg = G[j][c];
      for (int r = 0; r < j; ++r) tg -= Rl[r][j] * Rl[r][c];
      const float nsq   = __shfl(tg, j);     // trailG[j,j]
      const float alpha = Ts[j][j];
      const float norm  = sqrtf(nsq);
      const float beta  = (alpha >= 0.0f) ? -norm : norm;  // -sign(alpha)*norm
      const float tau   = (beta - alpha) / beta;
      const float scale = 1.0f / (alpha - beta);
      if (c > j) {
        const float wc = (tg - beta * Ts[j][c]) * scale;
        const float tw = tau * wc;
        // update T rows r = j..25 in column c (reads Ts[r][j]: broadcast)
        Ts[j][c] -= tw;                        // v_top[j] = 1
        for (int r = j + 1; r < QR_N; ++r)
          Ts[r][c] -= tw * (Ts[r][j] * scale);
        Rl[j][c] = Ts[j][c];                   // finalized row-j entry
      } else if (c == j) {
        Rl[j][j] = beta;
      }
    }
  }
  __syncthreads();

  // Phase 4: Q row r = solve y * R = A[r,:]; write f16 [512][32] (pad 0)
  float rinv[QR_N];
#pragma unroll
  for (int c = 0; c < QR_N; ++c) rinv[c] = 1.0f / Rl[c][c];

  float y[QR_N];
#pragma unroll
  for (int c = 0; c < QR_N; ++c) y[c] = As[tid][c];
#pragma unroll
  for (int c = 0; c < QR_N; ++c) {
    float s = y[c];
#pragma unroll
    for (int k = 0; k < c; ++k) s -= y[k] * Rl[k][c];
    y[c] = s * rinv[c];
  }
  _Float16* qrow = qf + (size_t)tid * 32;
#pragma unroll
  for (int c = 0; c < QR_N; ++c) qrow[c] = (_Float16)y[c];
#pragma unroll
  for (int c = QR_N; c < 32; ++c) qrow[c] = (_Float16)0.0f;
}

// ---------------------------------------------------------------------------
// Kernel 2 (unchanged, at write-BW floor): out[b,o] = sum_d x[b,d] * Q[o,d]
// via mfma_f32_16x16x32_f16 with LDS-transposed epilogue for coalesced
// dwordx4 stores. Block = 256 thr / 4 waves, 32 rows x 512 cols per iter.
// ---------------------------------------------------------------------------
__global__ __launch_bounds__(256, 4) void dir_matmul(const float* __restrict__ x,
                                                     const _Float16* __restrict__ qf,
                                                     float* __restrict__ out,
                                                     int nblk32) {
  const int tid   = threadIdx.x;
  const int wid   = tid >> 6;
  const int l     = tid & 63;
  const int rloc  = l & 15;
  const int grp   = l >> 4;
  const int k0    = grp * 8;
  const int rhalf = (wid >> 1) * 16;   // row half: 0 or 16
  const int chalf = (wid & 1) * 256;   // col half: 0 or 256
  const int t2b   = (wid & 1) * 16;    // N-tile base

  __shared__ float tile[4][16 * 132];  // per-wave 16x128 f32, pad 4
  float* tw = tile[wid];

  half8_t bq[16];
#pragma unroll
  for (int t2 = 0; t2 < 16; ++t2)
    bq[t2] = *reinterpret_cast<const half8_t*>(
        qf + (size_t)((t2b + t2) * 16 + rloc) * 32 + k0);

  for (int rb = blockIdx.x; rb < nblk32; rb += gridDim.x) {
    const int row = rb * 32 + rhalf + rloc;
    half8_t av;
    const float* xp = x + (size_t)row * QR_N + k0;
    if (grp < 3) {
#pragma unroll
      for (int e = 0; e < 4; ++e) {
        float2 v = *reinterpret_cast<const float2*>(xp + 2 * e);
        av[2 * e]     = (_Float16)v.x;
        av[2 * e + 1] = (_Float16)v.y;
      }
    } else {
      float2 v = *reinterpret_cast<const float2*>(xp);
      av[0] = (_Float16)v.x; av[1] = (_Float16)v.y;
#pragma unroll
      for (int e = 2; e < 8; ++e) av[e] = (_Float16)0.0f;
    }

#pragma unroll
    for (int cc = 0; cc < 2; ++cc) {
#pragma unroll
      for (int tt = 0; tt < 8; ++tt) {
        f32x4 acc = {0.0f, 0.0f, 0.0f, 0.0f};
        acc = __builtin_amdgcn_mfma_f32_16x16x32_f16(av, bq[cc * 8 + tt], acc, 0, 0, 0);
#pragma unroll
        for (int j = 0; j < 4; ++j)
          tw[(grp * 4 + j) * 132 + tt * 16 + rloc] = acc[j];
      }
      __syncthreads();
#pragma unroll
      for (int it = 0; it < 8; ++it) {
        const int r  = it * 2 + (l >> 5);
        const int cg = l & 31;
        f32x4 v = *reinterpret_cast<const f32x4*>(&tw[r * 132 + 4 * cg]);
        *reinterpret_cast<f32x4*>(
            out + (size_t)(rb * 32 + rhalf + r) * OUTC + chalf + cc * 128 + 4 * cg) = v;
      }
      __syncthreads();
    }
  }
}

extern "C" void kernel_launch(void* const* d_in, const int* in_sizes, int n_in,
                              void* d_out, int out_size, void* d_ws, size_t ws_size,
                              hipStream_t stream) {
  const float* input  = (const float*)d_in[0];   // [B, 26] f32
  const float* weight = (const float*)d_in[1];   // [512, 26] f32
  float* out = (float*)d_out;                    // [B, 512] f32
  _Float16* qf = (_Float16*)d_ws;                // [512][32] f16 scratch (32 KB)

  const int B = in_sizes[0] / QR_N;              // 262144
  const int nblk32 = B / 32;                     // 8192

  qr_kernel<<<1, 512, 0, stream>>>(weight, qf);
  dir_matmul<<<2048, 256, 0, stream>>>(input, qf, out, nblk32);
}

// Round 10
// 134.964 us; speedup vs baseline: 2.1986x; 1.1653x over previous
//
#include <hip/hip_runtime.h>
#include <math.h>

#define QR_M 512
#define QR_N 26
#define OUTC 512
#define LDP 30   // LDS row stride (floats): even (8B-aligned float2)

using half8_t = __attribute__((ext_vector_type(8))) _Float16;
using f32x4   = __attribute__((ext_vector_type(4))) float;

// ---------------------------------------------------------------------------
// Kernel 1: Gram-domain Householder QR, race-free phase 3.
//  Ph1: stage A = w+1e-8 into As[512][30] (float2).
//  Ph2: G = A^T A via 2x2 col-blocks x 4 row-chunks (barrier-protected
//       partials in LDS, then combine).
//  Ph3: wave 0 only, REGISTERS + shfl (no cross-lane LDS dependencies --
//       the round-9 failure was a compiler-legal hoist of row-j LDS reads
//       above prior-iteration row-c writes; shfl makes the cross-lane
//       dependency an explicit register dependency). Lane c holds column c
//       of G, T, R. Exact LAPACK slarfg recursion:
//         tg = G[j][c] - sum_{r<j} R[r][j]*R[r][c]
//            = gcol[j] - sum shfl(rcol[r],j)*rcol[r]
//         nsq = shfl(tg, j); alpha = shfl(tcol[j], j)
//         beta = -sign(alpha)*sqrt(nsq); tau=(beta-alpha)/beta;
//         scale = 1/(alpha-beta)
//         wc = (tg - beta*tcol[j])*scale; tw = (c>j) ? tau*wc : 0
//         tcol[j] -= tw;  rcol[j] = (c==j) ? beta : tcol[j]
//         tcol[rr] -= tw * (shfl(tcol[rr], j)*scale),  rr > j
//       R written to LDS (write-only) for phase 4.
//  Ph4 (after barrier): Q row t solves y*R = A[t,:] (cond~1.6, err ~1e-6),
//       broadcast float2 reads of Rt; emit Q as f16 [512][32], zero-padded.
// ---------------------------------------------------------------------------
__global__ __launch_bounds__(512) void qr_kernel(const float* __restrict__ w,
                                                 _Float16* __restrict__ qf) {
  const int tid  = threadIdx.x;
  const int lane = tid & 63;
  const int wid  = tid >> 6;

  __shared__ float As[QR_M][LDP];   // 61.4 KB
  __shared__ float Gs[QR_N][LDP];   // Gram (symmetric), row-major
  __shared__ float Rt[QR_N][LDP];   // Rt[c][j] = R[j][c]
  __shared__ float Gp[4][91][4];    // Gram partials [chunk][blk][2x2]

  // ---- Phase 1: stage A ----
  {
    const float2* wp = reinterpret_cast<const float2*>(w + (size_t)tid * QR_N);
    float2 v[13];
#pragma unroll
    for (int i = 0; i < 13; ++i) v[i] = wp[i];
#pragma unroll
    for (int i = 0; i < 13; ++i) {
      As[tid][2 * i]     = v[i].x + 1e-8f;
      As[tid][2 * i + 1] = v[i].y + 1e-8f;
    }
  }
  __syncthreads();

  // ---- Phase 2a: partial Gram (364 threads) ----
  if (tid < 364) {
    const int chunk = tid / 91;         // rows chunk*128..+127
    const int blk   = tid - chunk * 91; // upper-tri 2x2 block
    int cb = 0, rem = blk;
    while (rem >= 13 - cb) { rem -= 13 - cb; ++cb; }
    const int db = cb + rem;
    const int c0 = 2 * cb, d0 = 2 * db;
    float s00 = 0.f, s01 = 0.f, s10 = 0.f, s11 = 0.f;
    const int r0 = chunk * 128;
    for (int r = r0; r < r0 + 128; ++r) {
      const float2 ac = *reinterpret_cast<const float2*>(&As[r][c0]);
      const float2 ad = *reinterpret_cast<const float2*>(&As[r][d0]);
      s00 += ac.x * ad.x; s01 += ac.x * ad.y;
      s10 += ac.y * ad.x; s11 += ac.y * ad.y;
    }
    Gp[chunk][blk][0] = s00; Gp[chunk][blk][1] = s01;
    Gp[chunk][blk][2] = s10; Gp[chunk][blk][3] = s11;
  }
  __syncthreads();

  // ---- Phase 2b: combine partials -> Gs (symmetric) ----
  if (tid < 364) {
    const int blk = tid >> 2;
    const int v   = tid & 3;
    int cb = 0, rem = blk;
    while (rem >= 13 - cb) { rem -= 13 - cb; ++cb; }
    const int db = cb + rem;
    const float s = Gp[0][blk][v] + Gp[1][blk][v] + Gp[2][blk][v] + Gp[3][blk][v];
    const int c = 2 * cb + (v >> 1);
    const int d = 2 * db + (v & 1);
    Gs[c][d] = s;
    Gs[d][c] = s;
  }
  __syncthreads();

  // ---- Phase 3: 26-step recursion, wave 0, registers + shfl ----
  if (wid == 0) {
    const int c  = lane;
    const int cm = (c < QR_N) ? c : (QR_N - 1);  // lanes 26..63 carry dummies
    float gcol[QR_N], tcol[QR_N], rcol[QR_N];
#pragma unroll
    for (int r = 0; r < QR_N; ++r) gcol[r] = Gs[r][cm];  // G[r][c] (symmetric)
#pragma unroll
    for (int r = 0; r < QR_N; ++r) tcol[r] = As[r][cm];  // T[r][c] init = A
#pragma unroll
    for (int r = 0; r < QR_N; ++r) rcol[r] = 0.0f;

#pragma unroll
    for (int j = 0; j < QR_N; ++j) {
      float tg = gcol[j];
#pragma unroll
      for (int r = 0; r < QR_N; ++r) {
        if (r < j) tg -= __shfl(rcol[r], j) * rcol[r];
      }
      const float nsq   = __shfl(tg, j);
      const float alpha = __shfl(tcol[j], j);
      const float norm  = sqrtf(nsq);
      const float beta  = (alpha >= 0.0f) ? -norm : norm;  // -sign(alpha)*norm
      const float tau   = (beta - alpha) / beta;
      const float scale = 1.0f / (alpha - beta);
      const float wc    = (tg - beta * tcol[j]) * scale;
      const float tw    = (c > j) ? (tau * wc) : 0.0f;
      tcol[j] -= tw;                                   // lane j: tw=0
      rcol[j]  = (c == j) ? beta : tcol[j];
#pragma unroll
      for (int rr = 0; rr < QR_N; ++rr) {
        if (rr > j) {
          const float vtop = __shfl(tcol[rr], j) * scale;  // T[rr][j]*scale
          tcol[rr] -= tw * vtop;
        }
      }
      if (c >= j && c < QR_N) Rt[c][j] = rcol[j];      // write-only LDS
    }
  }
  __syncthreads();

  // ---- Phase 4: per-row solve y * R = A[t,:]; emit f16 [512][32] ----
  float rinv[QR_N];
#pragma unroll
  for (int cc = 0; cc < QR_N; ++cc) rinv[cc] = 1.0f / Rt[cc][cc];

  float y[QR_N];
#pragma unroll
  for (int cc = 0; cc < QR_N; ++cc) y[cc] = As[tid][cc];
#pragma unroll
  for (int cc = 0; cc < QR_N; ++cc) {
    float s = y[cc];
    int k = 0;
#pragma unroll
    for (; k + 1 < cc; k += 2) {
      const float2 rk = *reinterpret_cast<const float2*>(&Rt[cc][k]);  // bcast
      s -= y[k] * rk.x + y[k + 1] * rk.y;
    }
    if (k < cc) s -= y[k] * Rt[cc][k];
    y[cc] = s * rinv[cc];
  }

  half8_t h0, h1, h2, h3;
#pragma unroll
  for (int e = 0; e < 8; ++e) h0[e] = (_Float16)y[e];
#pragma unroll
  for (int e = 0; e < 8; ++e) h1[e] = (_Float16)y[8 + e];
#pragma unroll
  for (int e = 0; e < 8; ++e) h2[e] = (_Float16)y[16 + e];
  h3[0] = (_Float16)y[24]; h3[1] = (_Float16)y[25];
#pragma unroll
  for (int e = 2; e < 8; ++e) h3[e] = (_Float16)0.0f;
  half8_t* qrow = reinterpret_cast<half8_t*>(qf + (size_t)tid * 32);
  qrow[0] = h0; qrow[1] = h1; qrow[2] = h2; qrow[3] = h3;
}

// ---------------------------------------------------------------------------
// Kernel 2 (unchanged, at write-BW floor): out[b,o] = sum_d x[b,d] * Q[o,d]
// via mfma_f32_16x16x32_f16 with LDS-transposed epilogue for coalesced
// dwordx4 stores. Block = 256 thr / 4 waves, 32 rows x 512 cols per iter.
// ---------------------------------------------------------------------------
__global__ __launch_bounds__(256, 4) void dir_matmul(const float* __restrict__ x,
                                                     const _Float16* __restrict__ qf,
                                                     float* __restrict__ out,
                                                     int nblk32) {
  const int tid   = threadIdx.x;
  const int wid   = tid >> 6;
  const int l     = tid & 63;
  const int rloc  = l & 15;
  const int grp   = l >> 4;
  const int k0    = grp * 8;
  const int rhalf = (wid >> 1) * 16;   // row half: 0 or 16
  const int chalf = (wid & 1) * 256;   // col half: 0 or 256
  const int t2b   = (wid & 1) * 16;    // N-tile base

  __shared__ float tile[4][16 * 132];  // per-wave 16x128 f32, pad 4
  float* tw = tile[wid];

  half8_t bq[16];
#pragma unroll
  for (int t2 = 0; t2 < 16; ++t2)
    bq[t2] = *reinterpret_cast<const half8_t*>(
        qf + (size_t)((t2b + t2) * 16 + rloc) * 32 + k0);

  for (int rb = blockIdx.x; rb < nblk32; rb += gridDim.x) {
    const int row = rb * 32 + rhalf + rloc;
    half8_t av;
    const float* xp = x + (size_t)row * QR_N + k0;
    if (grp < 3) {
#pragma unroll
      for (int e = 0; e < 4; ++e) {
        float2 v = *reinterpret_cast<const float2*>(xp + 2 * e);
        av[2 * e]     = (_Float16)v.x;
        av[2 * e + 1] = (_Float16)v.y;
      }
    } else {
      float2 v = *reinterpret_cast<const float2*>(xp);
      av[0] = (_Float16)v.x; av[1] = (_Float16)v.y;
#pragma unroll
      for (int e = 2; e < 8; ++e) av[e] = (_Float16)0.0f;
    }

#pragma unroll
    for (int cc = 0; cc < 2; ++cc) {
#pragma unroll
      for (int tt = 0; tt < 8; ++tt) {
        f32x4 acc = {0.0f, 0.0f, 0.0f, 0.0f};
        acc = __builtin_amdgcn_mfma_f32_16x16x32_f16(av, bq[cc * 8 + tt], acc, 0, 0, 0);
#pragma unroll
        for (int j = 0; j < 4; ++j)
          tw[(grp * 4 + j) * 132 + tt * 16 + rloc] = acc[j];
      }
      __syncthreads();
#pragma unroll
      for (int it = 0; it < 8; ++it) {
        const int r  = it * 2 + (l >> 5);
        const int cg = l & 31;
        f32x4 v = *reinterpret_cast<const f32x4*>(&tw[r * 132 + 4 * cg]);
        *reinterpret_cast<f32x4*>(
            out + (size_t)(rb * 32 + rhalf + r) * OUTC + chalf + cc * 128 + 4 * cg) = v;
      }
      __syncthreads();
    }
  }
}

extern "C" void kernel_launch(void* const* d_in, const int* in_sizes, int n_in,
                              void* d_out, int out_size, void* d_ws, size_t ws_size,
                              hipStream_t stream) {
  const float* input  = (const float*)d_in[0];   // [B, 26] f32
  const float* weight = (const float*)d_in[1];   // [512, 26] f32
  float* out = (float*)d_out;                    // [B, 512] f32
  _Float16* qf = (_Float16*)d_ws;                // [512][32] f16 scratch (32 KB)

  const int B = in_sizes[0] / QR_N;              // 262144
  const int nblk32 = B / 32;                     // 8192

  qr_kernel<<<1, 512, 0, stream>>>(weight, qf);
  dir_matmul<<<2048, 256, 0, stream>>>(input, qf, out, nblk32);
}